// Round 1
// baseline (342.465 us; speedup 1.0000x reference)
//
#include <hip/hip_runtime.h>
#include <math.h>

// Problem constants (from reference setup_inputs)
#define NB 4        // batch
#define TT 8192     // sequence length
#define DM 1024     // d_model
#define NH 32       // half = N/2 modes (second 32 modes are discarded by reference)
#define CT 64       // timesteps per scan chunk (= one wave)
#define NG (TT/CT)  // 128 chunks per sequence
#define DK 128      // d-chunk for K1 LDS staging

// ---------------------------------------------------------------------------
// K1: x_proj = x @ W_in^T fused with per-chunk local complex scan.
// Block = 256 threads = 4 waves. Wave ng handles modes [8ng, 8ng+8); lane = t.
// LDS: xs transposed tile (pitch 129 -> conflict-free lane=t reads),
//      ws = W_in chunk (wave-uniform broadcast reads).
// ---------------------------------------------------------------------------
__global__ __launch_bounds__(256) void k1_proj_scan(
    const float* __restrict__ x, const float* __restrict__ Wi,
    const float* __restrict__ log_tau, const float* __restrict__ freq,
    const float* __restrict__ log_dt,
    float* __restrict__ hl, float* __restrict__ Ech)
{
    __shared__ __align__(16) float xs[CT * 129];
    __shared__ __align__(16) float ws[NH * DK];
    const int c    = blockIdx.x;
    const int b    = blockIdx.y;
    const int t0   = c * CT;
    const int tid  = threadIdx.x;
    const int lane = tid & 63;
    const int ng   = tid >> 6;

    float acc[8] = {0.f, 0.f, 0.f, 0.f, 0.f, 0.f, 0.f, 0.f};
    const float* xb = x + ((size_t)b * TT + t0) * DM;

    for (int dk = 0; dk < DM; dk += DK) {
        // stage x tile: 64 t x 128 d, float4 global loads, scalar LDS stores
#pragma unroll
        for (int it = 0; it < 8; ++it) {
            int idx4 = tid + it * 256;           // 0..2047
            int tt   = idx4 >> 5;                // 0..63
            int d4   = (idx4 & 31) * 4;          // 0..124
            float4 v = *(const float4*)(xb + (size_t)tt * DM + dk + d4);
            float* p = &xs[tt * 129 + d4];
            p[0] = v.x; p[1] = v.y; p[2] = v.z; p[3] = v.w;
        }
        // stage W_in chunk: 32 n x 128 d
#pragma unroll
        for (int it = 0; it < 4; ++it) {
            int idx4 = tid + it * 256;           // 0..1023
            int nn   = idx4 >> 5;
            int d4   = (idx4 & 31) * 4;
            *(float4*)(&ws[nn * DK + d4]) =
                *(const float4*)(Wi + (size_t)nn * DM + dk + d4);
        }
        __syncthreads();
#pragma unroll 2
        for (int d4 = 0; d4 < DK; d4 += 4) {
            const float* xrow = &xs[lane * 129 + d4];
            float x0 = xrow[0], x1 = xrow[1], x2 = xrow[2], x3 = xrow[3];
#pragma unroll
            for (int j = 0; j < 8; ++j) {
                const float4 w = *(const float4*)(&ws[(ng * 8 + j) * DK + d4]);
                acc[j] = fmaf(x3, w.w, fmaf(x2, w.z, fmaf(x1, w.y, fmaf(x0, w.x, acc[j]))));
            }
        }
        __syncthreads();
    }

    // Per-mode 64-step inclusive scan over lanes (t), Hillis-Steele with
    // lambda^(2^k) by repeated complex squaring.
    const float dtv = expf(log_dt[0]);
    for (int j = 0; j < 8; ++j) {
        const int n = ng * 8 + j;
        const float tau = fmaxf(expf(log_tau[n]), 1e-4f);
        const float rr  = expf(-tau * dtv);
        const float th  = freq[n] * dtv;
        float pr = rr * cosf(th), pi = rr * sinf(th);   // lambda
        float vr = acc[j], vi = 0.f;
#pragma unroll
        for (int off = 1; off < 64; off <<= 1) {
            float ur = __shfl_up(vr, (unsigned)off);
            float ui = __shfl_up(vi, (unsigned)off);
            if (lane >= off) {
                vr = fmaf(pr, ur, fmaf(-pi, ui, vr));
                vi = fmaf(pr, ui, fmaf( pi, ur, vi));
            }
            float sr = pr * pr - pi * pi;
            float si = 2.f * pr * pi;
            pr = sr; pi = si;
        }
        size_t hb = (((size_t)b * TT + t0 + lane) * NH + n) * 2;
        hl[hb]     = vr;
        hl[hb + 1] = vi;
        if (lane == 63) {                       // chunk end state
            size_t eb = (((size_t)b * NG + c) * NH + n) * 2;
            Ech[eb]     = vr;
            Ech[eb + 1] = vi;
        }
    }
}

// ---------------------------------------------------------------------------
// K2: inter-chunk scan. H[b][c][n] = sum_{c'<c} (lambda^64)^(c-1-c') E[b][c'][n]
// (Horner). Tiny kernel; powers computed in double for robustness.
// ---------------------------------------------------------------------------
__global__ __launch_bounds__(64) void k2_chunkscan(
    const float* __restrict__ log_tau, const float* __restrict__ freq,
    const float* __restrict__ log_dt,
    const float* __restrict__ Ech, float* __restrict__ Hin)
{
    const int n = threadIdx.x;
    if (n >= NH) return;
    const int c = blockIdx.x;
    const int b = blockIdx.y;
    const double dtv = exp((double)log_dt[0]);
    const double tau = fmax(exp((double)log_tau[n]), 1e-4);
    const double th  = (double)freq[n] * dtv;
    const double m   = exp(-tau * dtv * (double)CT);
    const double a   = th * (double)CT;
    const float Lr = (float)(m * cos(a));
    const float Li = (float)(m * sin(a));
    float hr = 0.f, hi = 0.f;
    for (int cp = 0; cp < c; ++cp) {
        const float* e = Ech + (((size_t)b * NG + cp) * NH + n) * 2;
        float tr = Lr * hr - Li * hi + e[0];
        float ti = Lr * hi + Li * hr + e[1];
        hr = tr; hi = ti;
    }
    float* o = Hin + (((size_t)b * NG + c) * NH + n) * 2;
    o[0] = hr; o[1] = hi;
}

// ---------------------------------------------------------------------------
// K3: combine phase (h = lambda^(t+1) * H_init + h_local, y = g*Re(h)) fused
// with output GEMM out = y @ W_out^T. W_out^T staged to LDS in 256-d chunks.
// Thread owns 16 t x 4 d; writes coalesced float4.
// ---------------------------------------------------------------------------
#define ROWFMA(i, s) \
    acc[i].x = fmaf(s, w.x, acc[i].x); acc[i].y = fmaf(s, w.y, acc[i].y); \
    acc[i].z = fmaf(s, w.z, acc[i].z); acc[i].w = fmaf(s, w.w, acc[i].w);

__global__ __launch_bounds__(256) void k3_out(
    const float* __restrict__ hl, const float* __restrict__ Hin,
    const float* __restrict__ Wo,
    const float* __restrict__ log_tau, const float* __restrict__ freq,
    const float* __restrict__ Bp, const float* __restrict__ Cp,
    const float* __restrict__ log_dt,
    float* __restrict__ out)
{
    __shared__ __align__(16) float ysT[NH * 64];    // [n][t]
    __shared__ __align__(16) float wT[NH * 260];    // [n][d_local], padded pitch
    const int c    = blockIdx.x;
    const int b    = blockIdx.y;
    const int t0   = c * CT;
    const int tid  = threadIdx.x;
    const int lane = tid & 63;
    const int ng   = tid >> 6;

    // Phase A: y[t][n] = g * Re(h_local + lambda^(t+1) * H_init)
    {
        const float dtv = expf(log_dt[0]);
        const int t = lane;
        for (int j = 0; j < 8; ++j) {
            const int n = ng * 8 + j;
            const float tau = fmaxf(expf(log_tau[n]), 1e-4f);
            const float rr  = expf(-tau * dtv);
            const float th  = freq[n] * dtv;
            const float g   = (fabsf(Bp[n]) + 1e-9f) * (fabsf(Cp[n]) + 1e-9f);
            float p2r = rr * cosf(th), p2i = rr * sinf(th);
            float pwr = 1.f, pwi = 0.f;
            const int e = t + 1;                 // 1..64: binary exponentiation
#pragma unroll
            for (int bit = 0; bit < 7; ++bit) {
                if (e & (1 << bit)) {
                    float nr = pwr * p2r - pwi * p2i;
                    float ni = pwr * p2i + pwi * p2r;
                    pwr = nr; pwi = ni;
                }
                float sr = p2r * p2r - p2i * p2i;
                float si = 2.f * p2r * p2i;
                p2r = sr; p2i = si;
            }
            const float* hp = hl  + (((size_t)b * TT + t0 + t) * NH + n) * 2;
            const float* Hp = Hin + (((size_t)b * NG + c) * NH + n) * 2;
            float re = hp[0] + pwr * Hp[0] - pwi * Hp[1];
            ysT[n * 64 + t] = g * re;
        }
    }
    __syncthreads();

    // Phase B: out[t][d] = sum_n y[t][n] * W_out[d][n]
    float* const outb = out + ((size_t)b * TT + t0) * DM;
    for (int db = 0; db < DM; db += 256) {
#pragma unroll
        for (int it = 0; it < 32; ++it) {
            int idx = tid + it * 256;            // 0..8191
            int dl  = idx >> 5;                  // 0..255
            int nn  = idx & 31;
            wT[nn * 260 + dl] = Wo[(size_t)(db + dl) * NH + nn];
        }
        __syncthreads();
        float4 acc[16];
#pragma unroll
        for (int i = 0; i < 16; ++i) acc[i] = make_float4(0.f, 0.f, 0.f, 0.f);
#pragma unroll 4
        for (int n = 0; n < NH; ++n) {
            const float4 w = *(const float4*)(&wT[n * 260 + lane * 4]);
            const float4* yp = (const float4*)(&ysT[n * 64 + ng * 16]);
            const float4 ya = yp[0], yb = yp[1], yc = yp[2], yd = yp[3];
            ROWFMA(0,  ya.x) ROWFMA(1,  ya.y) ROWFMA(2,  ya.z) ROWFMA(3,  ya.w)
            ROWFMA(4,  yb.x) ROWFMA(5,  yb.y) ROWFMA(6,  yb.z) ROWFMA(7,  yb.w)
            ROWFMA(8,  yc.x) ROWFMA(9,  yc.y) ROWFMA(10, yc.z) ROWFMA(11, yc.w)
            ROWFMA(12, yd.x) ROWFMA(13, yd.y) ROWFMA(14, yd.z) ROWFMA(15, yd.w)
        }
#pragma unroll
        for (int i = 0; i < 16; ++i) {
            *(float4*)(outb + (size_t)(ng * 16 + i) * DM + db + lane * 4) = acc[i];
        }
        __syncthreads();
    }
}

// ---------------------------------------------------------------------------
// Workspace layout (floats): hl [NB*TT*NH*2] (8 MB) | Ech [NB*NG*NH*2] (128KB)
// | Hin [NB*NG*NH*2] (128KB). Total ~8.65 MB required of d_ws.
// ---------------------------------------------------------------------------
extern "C" void kernel_launch(void* const* d_in, const int* in_sizes, int n_in,
                              void* d_out, int out_size, void* d_ws, size_t ws_size,
                              hipStream_t stream)
{
    (void)in_sizes; (void)n_in; (void)out_size; (void)ws_size;
    const float* x       = (const float*)d_in[0];
    const float* log_tau = (const float*)d_in[1];
    const float* freq    = (const float*)d_in[2];
    const float* Bp      = (const float*)d_in[3];
    const float* Cp      = (const float*)d_in[4];
    const float* log_dt  = (const float*)d_in[5];
    const float* Wi      = (const float*)d_in[6];
    const float* Wo      = (const float*)d_in[7];
    float* out = (float*)d_out;

    float* wsf = (float*)d_ws;
    float* hl  = wsf;                                  // NB*TT*NH*2 floats
    float* Ech = wsf + (size_t)NB * TT * NH * 2;       // NB*NG*NH*2 floats
    float* Hin = Ech + (size_t)NB * NG * NH * 2;       // NB*NG*NH*2 floats

    dim3 grid(NG, NB);
    k1_proj_scan<<<grid, 256, 0, stream>>>(x, Wi, log_tau, freq, log_dt, hl, Ech);
    k2_chunkscan<<<grid, 64, 0, stream>>>(log_tau, freq, log_dt, Ech, Hin);
    k3_out<<<grid, 256, 0, stream>>>(hl, Hin, Wo, log_tau, freq, Bp, Cp, log_dt, out);
}

// Round 2
// 320.128 us; speedup vs baseline: 1.0698x; 1.0698x over previous
//
#include <hip/hip_runtime.h>
#include <math.h>

// Problem constants (from reference setup_inputs)
#define NB 4        // batch
#define TT 8192     // sequence length
#define DM 1024     // d_model
#define NH 32       // half = N/2 modes (second 32 are discarded by reference)
#define CT 64       // timesteps per scan chunk (= one wave)
#define NG (TT/CT)  // 128 chunks per sequence
#define DK 128      // d-chunk for K1 LDS staging
#define MW 4        // modes per wave (8 waves x 4 modes = 32)

// ---------------------------------------------------------------------------
// K1: x_proj = x @ W_in^T fused with per-chunk local complex scan.
// Block = 512 threads = 8 waves; wave w owns modes [4w,4w+4); lane = t.
// xs pitch 129 (compute reads 2-way = free). Staging stores use per-lane
// rotation (instr k writes word (k + (lane>>3))&3) -> conflict-free.
// hl/Ech in chunk-major float2 layouts for coalesced writes.
// ---------------------------------------------------------------------------
__global__ __launch_bounds__(512, 4) void k1_proj_scan(
    const float* __restrict__ x, const float* __restrict__ Wi,
    const float* __restrict__ log_tau, const float* __restrict__ freq,
    const float* __restrict__ log_dt,
    float2* __restrict__ hl, float2* __restrict__ Ech)
{
    __shared__ float xs[CT * 129];      // 33 KB
    __shared__ float ws[NH * DK];       // 16 KB
    const int c    = blockIdx.x;
    const int b    = blockIdx.y;
    const int t0   = c * CT;
    const int tid  = threadIdx.x;
    const int lane = tid & 63;
    const int wv   = tid >> 6;          // 0..7

    float acc[MW] = {0.f, 0.f, 0.f, 0.f};
    const float* xb = x + ((size_t)b * TT + t0) * DM;

    for (int dk = 0; dk < DM; dk += DK) {
        // stage x tile: 64 t x 128 d (2048 float4 over 512 threads)
#pragma unroll
        for (int it = 0; it < 4; ++it) {
            int idx4 = tid + it * 512;            // 0..2047
            int tt   = idx4 >> 5;                 // 0..63
            int cc   = idx4 & 31;                 // 16B-column
            float4 v = *(const float4*)(xb + (size_t)tt * DM + dk + cc * 4);
            float vv[4] = {v.x, v.y, v.z, v.w};
            float* p = &xs[tt * 129 + cc * 4];
            int q = (idx4 >> 3) & 3;              // rotation group
#pragma unroll
            for (int k = 0; k < 4; ++k) { int j = (k + q) & 3; p[j] = vv[j]; }
        }
        // stage W_in chunk: 32 n x 128 d (1024 float4)
#pragma unroll
        for (int it = 0; it < 2; ++it) {
            int idx4 = tid + it * 512;            // 0..1023
            int nn   = idx4 >> 5;
            int d4   = (idx4 & 31) * 4;
            *(float4*)(&ws[nn * DK + d4]) =
                *(const float4*)(Wi + (size_t)nn * DM + dk + d4);
        }
        __syncthreads();
#pragma unroll 4
        for (int d4 = 0; d4 < DK; d4 += 4) {
            const float* xr = &xs[lane * 129 + d4];
            float x0 = xr[0], x1 = xr[1], x2 = xr[2], x3 = xr[3];
#pragma unroll
            for (int j = 0; j < MW; ++j) {
                const float4 w = *(const float4*)(&ws[(wv * MW + j) * DK + d4]);
                acc[j] = fmaf(x3, w.w, fmaf(x2, w.z, fmaf(x1, w.y, fmaf(x0, w.x, acc[j]))));
            }
        }
        __syncthreads();
    }

    // 64-step inclusive wave scan (Hillis-Steele, lambda^(2^k) by squaring)
    const float dtv = expf(log_dt[0]);
#pragma unroll
    for (int j = 0; j < MW; ++j) {
        const int n = wv * MW + j;
        const float tau = fmaxf(expf(log_tau[n]), 1e-4f);
        const float rr  = expf(-tau * dtv);
        const float th  = freq[n] * dtv;
        float pr = rr * cosf(th), pi = rr * sinf(th);
        float vr = acc[j], vi = 0.f;
#pragma unroll
        for (int off = 1; off < 64; off <<= 1) {
            float ur = __shfl_up(vr, (unsigned)off);
            float ui = __shfl_up(vi, (unsigned)off);
            if (lane >= off) {
                vr = fmaf(pr, ur, fmaf(-pi, ui, vr));
                vi = fmaf(pr, ui, fmaf( pi, ur, vi));
            }
            float sr = pr * pr - pi * pi;
            float si = 2.f * pr * pi;
            pr = sr; pi = si;
        }
        // hl layout [b][c][n][t] float2 -> coalesced 512B per mode
        hl[((size_t)(b * NG + c) * NH + n) * CT + lane] = make_float2(vr, vi);
        if (lane == 63) {
            Ech[((size_t)b * NH + n) * NG + c] = make_float2(vr, vi);
        }
    }
}

// ---------------------------------------------------------------------------
// K2: inter-chunk exclusive scan via wave Kogge-Stone. Lane l owns chunks
// {2l, 2l+1}; pair-combine then 6-step scan with ratio Lambda^2.
// Hin[c] = state BEFORE chunk c. Grid = NB blocks x 256 threads.
// ---------------------------------------------------------------------------
__global__ __launch_bounds__(256) void k2_chunkscan(
    const float* __restrict__ log_tau, const float* __restrict__ freq,
    const float* __restrict__ log_dt,
    const float2* __restrict__ Ech, float2* __restrict__ Hin)
{
    const int b    = blockIdx.x;
    const int lane = threadIdx.x & 63;
    const int wv   = threadIdx.x >> 6;      // 0..3, 8 modes each
    const double dtv = exp((double)log_dt[0]);
#pragma unroll
    for (int j = 0; j < 8; ++j) {
        const int n = wv * 8 + j;
        const double tau = fmax(exp((double)log_tau[n]), 1e-4);
        const double a   = (double)freq[n] * dtv * (double)CT;
        const double m   = exp(-tau * dtv * (double)CT);
        const float Lr = (float)(m * cos(a));   // Lambda = lambda^64
        const float Li = (float)(m * sin(a));
        const float2* eb = Ech + ((size_t)b * NH + n) * NG;
        float2 e0 = eb[2 * lane];
        float2 e1 = eb[2 * lane + 1];
        // pair combine: S = Lambda*e0 + e1 (state after chunk 2l from zero)
        float vr = fmaf(Lr, e0.x, fmaf(-Li, e0.y, e1.x));
        float vi = fmaf(Lr, e0.y, fmaf( Li, e0.x, e1.y));
        float pr = Lr * Lr - Li * Li;           // Lambda^2
        float pi = 2.f * Lr * Li;
#pragma unroll
        for (int off = 1; off < 64; off <<= 1) {
            float ur = __shfl_up(vr, (unsigned)off);
            float ui = __shfl_up(vi, (unsigned)off);
            if (lane >= off) {
                vr = fmaf(pr, ur, fmaf(-pi, ui, vr));
                vi = fmaf(pr, ui, fmaf( pi, ur, vi));
            }
            float sr = pr * pr - pi * pi;
            float si = 2.f * pr * pi;
            pr = sr; pi = si;
        }
        // v_l = state after chunk 2l+1; exclusive shift
        float wr = __shfl_up(vr, 1u), wi = __shfl_up(vi, 1u);
        if (lane == 0) { wr = 0.f; wi = 0.f; }
        float2* hb = Hin + ((size_t)b * NH + n) * NG;
        hb[2 * lane]     = make_float2(wr, wi);
        hb[2 * lane + 1] = make_float2(fmaf(Lr, wr, fmaf(-Li, wi, e0.x)),
                                       fmaf(Lr, wi, fmaf( Li, wr, e0.y)));
    }
}

// ---------------------------------------------------------------------------
// K3: combine (h = lambda^(t+1)*H_init + h_local, y = g*Re h) fused with
// output GEMM. 512 threads = 8 waves: wave = (d-quarter qd, t-group tg).
// wT pitch 513 with lane-linear reads (conflict-free); out stores are
// 4 coalesced 256B scalar stores per row.
// ---------------------------------------------------------------------------
__global__ __launch_bounds__(512, 4) void k3_out(
    const float2* __restrict__ hl, const float2* __restrict__ Hin,
    const float* __restrict__ Wo,
    const float* __restrict__ log_tau, const float* __restrict__ freq,
    const float* __restrict__ Bp, const float* __restrict__ Cp,
    const float* __restrict__ log_dt,
    float* __restrict__ out)
{
    __shared__ float ysT[NH * 64];      // 8 KB  [n][t]
    __shared__ float wT[NH * 513];      // 64.1 KB [n][d-in-512-chunk]
    const int c    = blockIdx.x;
    const int b    = blockIdx.y;
    const int t0   = c * CT;
    const int tid  = threadIdx.x;
    const int lane = tid & 63;
    const int wv   = tid >> 6;          // 0..7

    // Phase A: y[t][n] = g * Re(h_local + lambda^(t+1) * H_init); lane = t
    {
        const float dtv = expf(log_dt[0]);
        const int t = lane;
#pragma unroll
        for (int j = 0; j < 4; ++j) {
            const int n = wv * 4 + j;
            const float tau = fmaxf(expf(log_tau[n]), 1e-4f);
            const float rr  = expf(-tau * dtv);
            const float th  = freq[n] * dtv;
            const float g   = (fabsf(Bp[n]) + 1e-9f) * (fabsf(Cp[n]) + 1e-9f);
            float p2r = rr * cosf(th), p2i = rr * sinf(th);
            float pwr = 1.f, pwi = 0.f;
            const int e = t + 1;                 // lambda^(t+1), binary exp
#pragma unroll
            for (int bit = 0; bit < 7; ++bit) {
                if (e & (1 << bit)) {
                    float nr = pwr * p2r - pwi * p2i;
                    float ni = pwr * p2i + pwi * p2r;
                    pwr = nr; pwi = ni;
                }
                float sr = p2r * p2r - p2i * p2i;
                float si = 2.f * p2r * p2i;
                p2r = sr; p2i = si;
            }
            float2 hv = hl[((size_t)(b * NG + c) * NH + n) * CT + t];
            float2 Hv = Hin[((size_t)b * NH + n) * NG + c];
            ysT[n * 64 + t] = g * (hv.x + pwr * Hv.x - pwi * Hv.y);
        }
    }

    // Phase B: out[t][d] = sum_n y[t][n] * Wo[d][n]
    const int qd = wv >> 2;             // d-quarter within 512-chunk
    const int tg = wv & 3;              // rows 16tg..16tg+15
    const int dbase = qd * 256 + lane;
    float* const outb = out + ((size_t)b * TT + t0) * DM;
    for (int db = 0; db < DM; db += 512) {
        __syncthreads();                // ysT ready (1st iter) / wT reuse
        // stage Wo chunk transposed: [n][dl], pitch 513
#pragma unroll
        for (int it = 0; it < 32; ++it) {
            int idx = tid + it * 512;   // 0..16383
            int dl  = idx >> 5;         // 0..511
            int nn  = idx & 31;
            wT[nn * 513 + dl] = Wo[(size_t)(db + dl) * NH + nn];
        }
        __syncthreads();
        float a0[16], a1[16], a2[16], a3[16];
#pragma unroll
        for (int i = 0; i < 16; ++i) { a0[i] = a1[i] = a2[i] = a3[i] = 0.f; }
#pragma unroll 4
        for (int n = 0; n < NH; ++n) {
            const float w0 = wT[n * 513 + dbase];
            const float w1 = wT[n * 513 + dbase + 64];
            const float w2 = wT[n * 513 + dbase + 128];
            const float w3 = wT[n * 513 + dbase + 192];
            const float* yr = &ysT[n * 64 + tg * 16];
#pragma unroll
            for (int i = 0; i < 16; ++i) {
                const float yv = yr[i];
                a0[i] = fmaf(yv, w0, a0[i]);
                a1[i] = fmaf(yv, w1, a1[i]);
                a2[i] = fmaf(yv, w2, a2[i]);
                a3[i] = fmaf(yv, w3, a3[i]);
            }
        }
#pragma unroll
        for (int i = 0; i < 16; ++i) {
            float* op = outb + (size_t)(tg * 16 + i) * DM + db + dbase;
            op[0]   = a0[i];
            op[64]  = a1[i];
            op[128] = a2[i];
            op[192] = a3[i];
        }
    }
}

// ---------------------------------------------------------------------------
// Workspace (floats): hl [NB*NG*NH*CT*2] (8.4 MB) | Ech [NB*NH*NG*2] (128KB)
// | Hin [NB*NH*NG*2] (128KB). Total ~8.65 MB of d_ws.
// ---------------------------------------------------------------------------
extern "C" void kernel_launch(void* const* d_in, const int* in_sizes, int n_in,
                              void* d_out, int out_size, void* d_ws, size_t ws_size,
                              hipStream_t stream)
{
    (void)in_sizes; (void)n_in; (void)out_size; (void)ws_size;
    const float* x       = (const float*)d_in[0];
    const float* log_tau = (const float*)d_in[1];
    const float* freq    = (const float*)d_in[2];
    const float* Bp      = (const float*)d_in[3];
    const float* Cp      = (const float*)d_in[4];
    const float* log_dt  = (const float*)d_in[5];
    const float* Wi      = (const float*)d_in[6];
    const float* Wo      = (const float*)d_in[7];
    float* out = (float*)d_out;

    float2* hl  = (float2*)d_ws;                               // NB*NG*NH*CT
    float2* Ech = hl  + (size_t)NB * NG * NH * CT;             // NB*NH*NG
    float2* Hin = Ech + (size_t)NB * NH * NG;                  // NB*NH*NG

    dim3 grid(NG, NB);
    k1_proj_scan<<<grid, 512, 0, stream>>>(x, Wi, log_tau, freq, log_dt, hl, Ech);
    k2_chunkscan<<<NB, 256, 0, stream>>>(log_tau, freq, log_dt, Ech, Hin);
    k3_out<<<grid, 512, 0, stream>>>(hl, Hin, Wo, log_tau, freq, Bp, Cp, log_dt, out);
}